// Round 8
// baseline (466.929 us; speedup 1.0000x reference)
//
#include <hip/hip_runtime.h>

#define NN 50000
#define NPGc 100
#define NG 500
#define DEG 32
#define HC 128
#define HID 64

__device__ __forceinline__ float lrelu(float x) { return x > 0.0f ? x : 0.2f * x; }

// ---- prep: Wa[K][4] = [ W@as_h0 | W@as_h1 | W@ad_h0 | W@ad_h1 ] for both layers ----
__global__ void k_prep(const float* __restrict__ W1, const float* __restrict__ as1,
                       const float* __restrict__ ad1, float* __restrict__ Wa1,
                       const float* __restrict__ W2, const float* __restrict__ as2,
                       const float* __restrict__ ad2, float* __restrict__ Wa2) {
  const float* W  = blockIdx.x ? W2 : W1;
  const float* as_ = blockIdx.x ? as2 : as1;
  const float* ad_ = blockIdx.x ? ad2 : ad1;
  float* Wa = blockIdx.x ? Wa2 : Wa1;
  int K = blockIdx.x ? 64 : 100;
  int t = threadIdx.x;
  for (int u = t; u < K * 4; u += blockDim.x) {
    int k = u >> 2, s = u & 3;
    const float* a = (s < 2) ? as_ : ad_;
    int h = s & 1;
    float acc = 0.f;
    for (int c = 0; c < 64; ++c) acc += W[k * 128 + h * 64 + c] * a[h * 64 + c];
    Wa[k * 4 + s] = acc;
  }
}

// ---- fused layer: per-(graph,head) block. K-chunked staging (smaller LDS ->
//      3 blocks/CU) + 4-deep W prefetch (ILP covers L2 latency). ----
template <int K, bool BN>
__global__ __launch_bounds__(256) void k_layer(
    const float* __restrict__ in, const float* __restrict__ W,
    const float* __restrict__ Wa, const float* __restrict__ AB,
    const int* __restrict__ esrc, const float* __restrict__ bg,
    float* __restrict__ gout) {
  constexpr int CH = (K == 100) ? 52 : 32;     // chunk-0 cols (chunk-1 = K-CH)
  constexpr int SP = (K == 100) ? 56 : 36;     // xbuf row stride (mult of 4)
  constexpr int XBB = NPGc * SP * 4;           // xbuf bytes
  constexpr int UBB = (XBB > 20832) ? XBB : 20832;
  __shared__ __align__(16) float xph[NPGc * 64];   // 25.6 KB
  __shared__ __align__(16) char ubuf[UBB];         // chunks: xbuf ; later: srcl|sc|alpha
  float* xbuf = (float*)ubuf;
  unsigned short* srcl = (unsigned short*)ubuf;    // 6400 B
  float* sc = (float*)(ubuf + 6400);               // 800 B
  float* alpha = (float*)(ubuf + 7232);            // 13600 B (tot 20832 <= UBB)

  int t = threadIdx.x;
  int g = blockIdx.x >> 1, h = blockIdx.x & 1;
  int base = g * NPGc;
  int ng = t >> 4, cg = t & 15;                    // 16 node-groups x 16 col-f4
  int wo = h * 16 + cg;                            // W float4 col offset

  float4 acc[7];
#pragma unroll
  for (int i = 0; i < 7; ++i) acc[i] = make_float4(0.f, 0.f, 0.f, 0.f);
  float myscore = 0.f;
  const float4* W4 = (const float4*)W;
  const float4* in4 = (const float4*)in;

#pragma unroll
  for (int c = 0; c < 2; ++c) {
    const int k0 = c ? CH : 0;
    const int cols = c ? (K - CH) : CH;
    const int QC = cols / 4;
    // stage chunk (BN-folded for layer 2)
    for (int u = t; u < NPGc * QC; u += 256) {
      int r = u / QC, q = u % QC;
      float4 v = in4[(size_t)(base + r) * (K / 4) + k0 / 4 + q];
      if (BN) {
        float4 a4 = ((const float4*)AB)[k0 / 4 + q];
        float4 b4 = ((const float4*)(AB + 64))[k0 / 4 + q];
        v.x = v.x * a4.x + b4.x; v.y = v.y * a4.y + b4.y;
        v.z = v.z * a4.z + b4.z; v.w = v.w * a4.w + b4.w;
      }
      ((float4*)(xbuf + r * SP))[q] = v;
    }
    __syncthreads();

    // GEMM chunk: 4-deep W prefetch, static register names
#define FMASTEP(kk_, w_) { \
    _Pragma("unroll") \
    for (int i = 0; i < 6; ++i) { \
      float a_ = xbuf[(ng + 16 * i) * SP + (kk_)]; \
      acc[i].x += a_ * w_.x; acc[i].y += a_ * w_.y; \
      acc[i].z += a_ * w_.z; acc[i].w += a_ * w_.w; } \
    if (ng < 4) { float a_ = xbuf[(ng + 96) * SP + (kk_)]; \
      acc[6].x += a_ * w_.x; acc[6].y += a_ * w_.y; \
      acc[6].z += a_ * w_.z; acc[6].w += a_ * w_.w; } }

    {
      float4 w0 = W4[(k0 + 0) * 32 + wo];
      float4 w1 = W4[(k0 + 1) * 32 + wo];
      float4 w2 = W4[(k0 + 2) * 32 + wo];
      float4 w3 = W4[(k0 + 3) * 32 + wo];
      for (int kk = 0; kk < cols; kk += 4) {
        int kn = k0 + kk + 4;
        bool more = (kk + 4) < cols;
        float4 n0, n1, n2, n3;
        if (more) {
          n0 = W4[(kn + 0) * 32 + wo]; n1 = W4[(kn + 1) * 32 + wo];
          n2 = W4[(kn + 2) * 32 + wo]; n3 = W4[(kn + 3) * 32 + wo];
        }
        FMASTEP(kk + 0, w0) FMASTEP(kk + 1, w1)
        FMASTEP(kk + 2, w2) FMASTEP(kk + 3, w3)
        if (more) { w0 = n0; w1 = n1; w2 = n2; w3 = n3; }
      }
    }
#undef FMASTEP
    // score contribution from this chunk
    if (t < 200) {
      int node = t >> 1, s = t & 1;
      for (int kk = 0; kk < cols; ++kk)
        myscore += xbuf[node * SP + kk] * Wa[(k0 + kk) * 4 + s * 2 + h];
    }
    __syncthreads();   // chunk reads done; xbuf reusable
  }

  // spill xph
#pragma unroll
  for (int i = 0; i < 6; ++i) ((float4*)xph)[(ng + 16 * i) * 16 + cg] = acc[i];
  if (ng < 4) ((float4*)xph)[(ng + 96) * 16 + cg] = acc[6];

  // phase C: spill scores, load local src ids (ubuf overlaid)
  if (t < 200) sc[(t & 1) * NPGc + (t >> 1)] = myscore;
  for (int u = t; u < NPGc * DEG; u += 256)
    srcl[u] = (unsigned short)(esrc[base * DEG + u] - base);
  __syncthreads();

  // phase D: edge softmax per dst (32 edges + self-loop)
  if (t < NPGc) {
    float sd = sc[NPGc + t];
    float es = lrelu(sc[t] + sd);
    float m = es;
    float e[DEG];
#pragma unroll
    for (int j = 0; j < DEG; ++j) {
      e[j] = lrelu(sc[srcl[t * DEG + j]] + sd);
      m = fmaxf(m, e[j]);
    }
    float exs = __expf(es - m);
    float den = exs;
#pragma unroll
    for (int j = 0; j < DEG; ++j) { e[j] = __expf(e[j] - m); den += e[j]; }
    float inv = 1.0f / den;
    float* al = alpha + t * (DEG + 2);
#pragma unroll
    for (int j = 0; j < DEG; ++j) al[j] = e[j] * inv;
    al[DEG] = exs * inv;
  }
  __syncthreads();

  // phase E: aggregate + bias -> gout cols [h*64, h*64+64)
  float4 bgv = ((const float4*)bg)[h * 16 + cg];
  for (int d = ng; d < NPGc; d += 16) {
    const float* al = alpha + d * (DEG + 2);
    const unsigned short* sp = srcl + d * DEG;
    float aself = al[DEG];
    float4 x4 = ((float4*)xph)[d * 16 + cg];
    float4 a2;
    a2.x = aself * x4.x; a2.y = aself * x4.y;
    a2.z = aself * x4.z; a2.w = aself * x4.w;
#pragma unroll 8
    for (int j = 0; j < DEG; ++j) {
      float a = al[j];
      float4 v = ((float4*)xph)[(int)sp[j] * 16 + cg];
      a2.x += a * v.x; a2.y += a * v.y;
      a2.z += a * v.z; a2.w += a * v.w;
    }
    a2.x += bgv.x; a2.y += bgv.y; a2.z += bgv.z; a2.w += bgv.w;
    ((float4*)gout)[(size_t)(base + d) * 32 + h * 16 + cg] = a2;
  }
}

// ---- out-GEMM: h = lrelu(g@lW + lb); lW streamed with 4-deep prefetch ----
__global__ __launch_bounds__(256) void k_out_gemm(
    const float* __restrict__ gin, const float* __restrict__ lW,
    const float* __restrict__ lb, float* __restrict__ h,
    float* __restrict__ partial) {
  __shared__ __align__(16) float gl[64 * 132];           // 33.8 KB
  __shared__ float psum[2 * HID];
  int t = threadIdx.x;
  int n0 = blockIdx.x * 64;

  for (int u = t; u < 64 * 32; u += 256) {
    int r = u >> 5, q = u & 31;
    int n = n0 + r;
    float4 v = make_float4(0.f, 0.f, 0.f, 0.f);
    if (n < NN) v = ((const float4*)(gin + (size_t)n * HC))[q];
    ((float4*)(gl + r * 132))[q] = v;
  }
  if (t < 2 * HID) psum[t] = 0.f;
  __syncthreads();

  int ng = t >> 4, cg = t & 15;   // 16 node-groups x 16 col-groups(float4)
  int r0 = ng * 4;
  float4 acc[4];
#pragma unroll
  for (int i = 0; i < 4; ++i) acc[i] = make_float4(0.f, 0.f, 0.f, 0.f);

#define OSTEP(k_, w_) { \
  _Pragma("unroll") \
  for (int i = 0; i < 4; ++i) { \
    float a_ = gl[(r0 + i) * 132 + (k_)]; \
    acc[i].x += a_ * w_.x; acc[i].y += a_ * w_.y; \
    acc[i].z += a_ * w_.z; acc[i].w += a_ * w_.w; } }

  const float4* lW4 = (const float4*)lW;
  {
    float4 w0 = lW4[0 * 16 + cg];
    float4 w1 = lW4[1 * 16 + cg];
    float4 w2 = lW4[2 * 16 + cg];
    float4 w3 = lW4[3 * 16 + cg];
    for (int k = 0; k < HC; k += 4) {
      int kn = k + 4;
      bool more = kn < HC;
      float4 n0, n1, n2, n3;
      if (more) {
        n0 = lW4[(kn + 0) * 16 + cg]; n1 = lW4[(kn + 1) * 16 + cg];
        n2 = lW4[(kn + 2) * 16 + cg]; n3 = lW4[(kn + 3) * 16 + cg];
      }
      OSTEP(k + 0, w0) OSTEP(k + 1, w1) OSTEP(k + 2, w2) OSTEP(k + 3, w3)
      if (more) { w0 = n0; w1 = n1; w2 = n2; w3 = n3; }
    }
  }
#undef OSTEP
  float4 bias = ((const float4*)lb)[cg];
  float s0 = 0, s1 = 0, s2 = 0, s3 = 0, q0 = 0, q1 = 0, q2 = 0, q3 = 0;
#pragma unroll
  for (int i = 0; i < 4; ++i) {
    int n = n0 + r0 + i;
    if (n < NN) {
      float4 v;
      v.x = lrelu(acc[i].x + bias.x); v.y = lrelu(acc[i].y + bias.y);
      v.z = lrelu(acc[i].z + bias.z); v.w = lrelu(acc[i].w + bias.w);
      ((float4*)(h + (size_t)n * HID))[cg] = v;
      s0 += v.x; q0 += v.x * v.x; s1 += v.y; q1 += v.y * v.y;
      s2 += v.z; q2 += v.z * v.z; s3 += v.w; q3 += v.w * v.w;
    }
  }
  int c0 = cg * 4;
  atomicAdd(&psum[c0 + 0], s0); atomicAdd(&psum[c0 + 1], s1);
  atomicAdd(&psum[c0 + 2], s2); atomicAdd(&psum[c0 + 3], s3);
  atomicAdd(&psum[HID + c0 + 0], q0); atomicAdd(&psum[HID + c0 + 1], q1);
  atomicAdd(&psum[HID + c0 + 2], q2); atomicAdd(&psum[HID + c0 + 3], q3);
  __syncthreads();
  if (t < 2 * HID) partial[blockIdx.x * 128 + t] = psum[t];
}

// ---- stats: reduce partials -> BN fold coefficients A,B ----
__global__ __launch_bounds__(256) void k_stats(
    const float* __restrict__ partial, int nb, const float* __restrict__ gamma,
    const float* __restrict__ beta, float* __restrict__ AB) {
  __shared__ float red[2][256];
  int c = blockIdx.x, t = threadIdx.x;
  float s = 0.f, sq = 0.f;
  for (int i = t; i < nb; i += 256) {
    s += partial[i * 128 + c];
    sq += partial[i * 128 + 64 + c];
  }
  red[0][t] = s; red[1][t] = sq;
  __syncthreads();
  for (int o = 128; o > 0; o >>= 1) {
    if (t < o) { red[0][t] += red[0][t + o]; red[1][t] += red[1][t + o]; }
    __syncthreads();
  }
  if (t == 0) {
    float mean = red[0][0] / (float)NN;
    float var = red[1][0] / (float)NN - mean * mean;
    float A = gamma[c] * rsqrtf(var + 1e-5f);
    AB[c] = A;
    AB[64 + c] = beta[c] - mean * A;
  }
}

// ---- pool + MLP head: per-graph mean of BN(h2) -> 64 -> 32 -> 2 ----
__global__ __launch_bounds__(64) void k_pool_mlp(
    const float* __restrict__ h2, const float* __restrict__ AB,
    const float* __restrict__ f1W, const float* __restrict__ f1b,
    const float* __restrict__ f2W, const float* __restrict__ f2b,
    const float* __restrict__ f3W, const float* __restrict__ f3b,
    float* __restrict__ out) {
  __shared__ float pp[4 * 64];
  __shared__ float pooled[64];
  __shared__ float z1[64];
  __shared__ float z2[32];
  int g = blockIdx.x, t = threadIdx.x;
  const float4* hb4 = (const float4*)(h2 + (size_t)g * NPGc * HID);
  int rq = t >> 4, c4 = t & 15;
  float4 s4 = make_float4(0.f, 0.f, 0.f, 0.f);
  for (int r = rq; r < NPGc; r += 4) {
    float4 v = hb4[r * 16 + c4];
    s4.x += v.x; s4.y += v.y; s4.z += v.z; s4.w += v.w;
  }
  ((float4*)pp)[rq * 16 + c4] = s4;
  __syncthreads();
  pooled[t] = (pp[t] + pp[64 + t] + pp[128 + t] + pp[192 + t]) * (1.0f / NPGc) * AB[t] + AB[64 + t];
  __syncthreads();
  float a = f1b[t];
  for (int c = 0; c < 64; ++c) a += pooled[c] * f1W[c * 64 + t];
  z1[t] = lrelu(a);
  __syncthreads();
  if (t < 32) {
    float a2 = f2b[t];
    for (int c = 0; c < 64; ++c) a2 += z1[c] * f2W[c * 32 + t];
    z2[t] = lrelu(a2);
  }
  __syncthreads();
  if (t < 2) {
    float a3 = f3b[t];
    for (int c = 0; c < 32; ++c) a3 += z2[c] * f3W[c * 2 + t];
    out[g * 2 + t] = a3;
  }
}

extern "C" void kernel_launch(void* const* d_in, const int* in_sizes, int n_in,
                              void* d_out, int out_size, void* d_ws, size_t ws_size,
                              hipStream_t stream) {
  const float* x   = (const float*)d_in[0];
  const float* W1  = (const float*)d_in[2];
  const float* as1 = (const float*)d_in[3];
  const float* ad1 = (const float*)d_in[4];
  const float* bg1 = (const float*)d_in[5];
  const float* l1W = (const float*)d_in[6];
  const float* l1b = (const float*)d_in[7];
  const float* g1  = (const float*)d_in[8];
  const float* b1  = (const float*)d_in[9];
  const float* W2  = (const float*)d_in[10];
  const float* as2 = (const float*)d_in[11];
  const float* ad2 = (const float*)d_in[12];
  const float* bg2 = (const float*)d_in[13];
  const float* l2W = (const float*)d_in[14];
  const float* l2b = (const float*)d_in[15];
  const float* g2  = (const float*)d_in[16];
  const float* b2  = (const float*)d_in[17];
  const float* f1W = (const float*)d_in[18];
  const float* f1b = (const float*)d_in[19];
  const float* f2W = (const float*)d_in[20];
  const float* f2b = (const float*)d_in[21];
  const float* f3W = (const float*)d_in[22];
  const float* f3b = (const float*)d_in[23];
  const int* esrc  = (const int*)d_in[24];   // row 0 of edge_index
  float* out = (float*)d_out;

  float* ws = (float*)d_ws;
  size_t off = 0;
  auto alloc = [&](size_t nf) { float* p = ws + off; off += (nf + 63) & ~(size_t)63; return p; };
  float* Wa1     = alloc(100 * 4);
  float* Wa2     = alloc(64 * 4);
  float* gout    = alloc((size_t)NN * HC);
  float* hbuf    = alloc((size_t)NN * HID);
  const int NB = (NN + 63) / 64;   // 782
  float* partial = alloc((size_t)NB * 128);
  float* AB1     = alloc(128);
  float* AB2     = alloc(128);
  (void)in_sizes; (void)n_in; (void)out_size; (void)ws_size;

  k_prep<<<2, 256, 0, stream>>>(W1, as1, ad1, Wa1, W2, as2, ad2, Wa2);
  k_layer<100, false><<<NG * 2, 256, 0, stream>>>(x, W1, Wa1, nullptr, esrc, bg1, gout);
  k_out_gemm<<<NB, 256, 0, stream>>>(gout, l1W, l1b, hbuf, partial);
  k_stats<<<64, 256, 0, stream>>>(partial, NB, g1, b1, AB1);
  k_layer<64, true><<<NG * 2, 256, 0, stream>>>(hbuf, W2, Wa2, AB1, esrc, bg2, gout);
  k_out_gemm<<<NB, 256, 0, stream>>>(gout, l2W, l2b, hbuf, partial);
  k_stats<<<64, 256, 0, stream>>>(partial, NB, g2, b2, AB2);
  k_pool_mlp<<<NG, 64, 0, stream>>>(hbuf, AB2, f1W, f1b, f2W, f2b, f3W, f3b, out);
}

// Round 11
// 326.781 us; speedup vs baseline: 1.4289x; 1.4289x over previous
//
#include <hip/hip_runtime.h>

#define NN 50000
#define NPGc 100
#define NG 500
#define DEG 32
#define HC 128
#define HID 64

__device__ __forceinline__ float lrelu(float x) { return x > 0.0f ? x : 0.2f * x; }

// ---- prep: Wa[K][4] = [ W@as_h0 | W@as_h1 | W@ad_h0 | W@ad_h1 ] for both layers ----
__global__ void k_prep(const float* __restrict__ W1, const float* __restrict__ as1,
                       const float* __restrict__ ad1, float* __restrict__ Wa1,
                       const float* __restrict__ W2, const float* __restrict__ as2,
                       const float* __restrict__ ad2, float* __restrict__ Wa2) {
  const float* W  = blockIdx.x ? W2 : W1;
  const float* as_ = blockIdx.x ? as2 : as1;
  const float* ad_ = blockIdx.x ? ad2 : ad1;
  float* Wa = blockIdx.x ? Wa2 : Wa1;
  int K = blockIdx.x ? 64 : 100;
  int t = threadIdx.x;
  for (int u = t; u < K * 4; u += blockDim.x) {
    int k = u >> 2, s = u & 3;
    const float* a = (s < 2) ? as_ : ad_;
    int h = s & 1;
    float acc = 0.f;
    for (int c = 0; c < 64; ++c) acc += W[k * 128 + h * 64 + c] * a[h * 64 + c];
    Wa[k * 4 + s] = acc;
  }
}

// ---- in-GEMM, per-(node-tile, head) block: 64 nodes x 64 cols.
//      W half = 25.6 KB -> L1-resident stream; LDS = xs only -> 6 blocks/CU. ----
template <int K, bool BN>
__global__ __launch_bounds__(256) void k_in_gemm(
    const float* __restrict__ in, const float* __restrict__ W,
    const float* __restrict__ Wa, const float* __restrict__ AB,
    float* __restrict__ xp, float* __restrict__ ssrc, float* __restrict__ sdst) {
  constexpr int KP = (K % 8 == 0) ? K + 4 : K;   // pad when K%8==0 (bank spread)
  __shared__ __align__(16) float xs[64 * KP];    // 25.6 KB (K=100) / 17.4 KB (K=64)
  int t = threadIdx.x;
  int b = blockIdx.x >> 1, h = blockIdx.x & 1;
  int n0 = b * 64;

  constexpr int RQ = K / 4;
  for (int u = t; u < 64 * RQ; u += 256) {
    int r = u / RQ, q = u % RQ;
    int n = n0 + r;
    float4 v = make_float4(0.f, 0.f, 0.f, 0.f);
    if (n < NN) v = ((const float4*)(in + (size_t)n * K))[q];
    if (BN) {
      float4 a4 = ((const float4*)AB)[q];
      float4 b4 = ((const float4*)(AB + 64))[q];
      v.x = v.x * a4.x + b4.x; v.y = v.y * a4.y + b4.y;
      v.z = v.z * a4.z + b4.z; v.w = v.w * a4.w + b4.w;
    }
    ((float4*)(xs + r * KP))[q] = v;
  }
  __syncthreads();

  int ng = t >> 4, cg = t & 15;   // 16 node-groups x 16 col-f4 (of this head)
  int r0 = ng * 4;
  int wo = h * 16 + cg;
  float4 acc[4];
#pragma unroll
  for (int i = 0; i < 4; ++i) acc[i] = make_float4(0.f, 0.f, 0.f, 0.f);

  const float4* W4 = (const float4*)W;
  float4 w4 = W4[wo];                       // k=0 prefetch (L1-hot after first rounds)
  for (int k = 0; k < K; ++k) {
    float4 wc = w4;
    if (k + 1 < K) w4 = W4[(k + 1) * 32 + wo];
#pragma unroll
    for (int i = 0; i < 4; ++i) {
      float a = xs[(r0 + i) * KP + k];
      acc[i].x += a * wc.x; acc[i].y += a * wc.y;
      acc[i].z += a * wc.z; acc[i].w += a * wc.w;
    }
  }
#pragma unroll
  for (int i = 0; i < 4; ++i) {
    int n = n0 + r0 + i;
    if (n < NN) ((float4*)(xp + (size_t)n * HC))[wo] = acc[i];
  }
  // score columns for this head: 64 nodes x {src,dst}
  if (t < 128) {
    int r = t >> 1, s = t & 1;
    float sc = 0.f;
    for (int k = 0; k < K; ++k) sc += xs[r * KP + k] * Wa[k * 4 + s * 2 + h];
    int n = n0 + r;
    if (n < NN) {
      if (s == 0) ssrc[n * 2 + h] = sc;
      else        sdst[n * 2 + h] = sc;
    }
  }
}

// ---- GAT: per-(graph,head) block; edge softmax + aggregation from LDS ----
__global__ __launch_bounds__(256) void k_gat(
    const float* __restrict__ xp, const float* __restrict__ ssrc,
    const float* __restrict__ sdst, const int* __restrict__ esrc,
    const float* __restrict__ bg, float* __restrict__ out) {
  __shared__ __align__(16) float xl[NPGc * 64];          // 25.6 KB (this head's cols)
  __shared__ float sh[NPGc];
  __shared__ float sdh[NPGc];
  __shared__ unsigned short srcl[NPGc * DEG];            // 6.4 KB
  __shared__ float alpha[NPGc * (DEG + 2)];              // 13.6 KB
  int t = threadIdx.x;
  int g = blockIdx.x >> 1, h = blockIdx.x & 1;
  int base = g * NPGc;

  const float4* xp4 = (const float4*)(xp + (size_t)base * HC);
  for (int u = t; u < NPGc * 16; u += 256)
    ((float4*)xl)[u] = xp4[(u >> 4) * 32 + h * 16 + (u & 15)];
  if (t < NPGc) {
    sh[t] = ssrc[(base + t) * 2 + h];
    sdh[t] = sdst[(base + t) * 2 + h];
  }
  for (int u = t; u < NPGc * DEG; u += 256)
    srcl[u] = (unsigned short)(esrc[base * DEG + u] - base);
  __syncthreads();

  if (t < NPGc) {
    float sd = sdh[t];
    float es = lrelu(sh[t] + sd);   // self-loop score
    float m = es;
    float e[DEG];
#pragma unroll
    for (int j = 0; j < DEG; ++j) {
      e[j] = lrelu(sh[srcl[t * DEG + j]] + sd);
      m = fmaxf(m, e[j]);
    }
    float exs = __expf(es - m);
    float den = exs;
#pragma unroll
    for (int j = 0; j < DEG; ++j) { e[j] = __expf(e[j] - m); den += e[j]; }
    float inv = 1.0f / den;
    float* al = alpha + t * (DEG + 2);
#pragma unroll
    for (int j = 0; j < DEG; ++j) al[j] = e[j] * inv;
    al[DEG] = exs * inv;
  }
  __syncthreads();

  int c4 = t & 15;                         // loop-invariant (256 % 16 == 0)
  float4 bgv = ((const float4*)bg)[h * 16 + c4];
  for (int d = t >> 4; d < NPGc; d += 16) {
    const float* al = alpha + d * (DEG + 2);
    const unsigned short* sp = srcl + d * DEG;
    float aself = al[DEG];
    float4 x4 = ((float4*)xl)[d * 16 + c4];
    float4 acc;
    acc.x = aself * x4.x; acc.y = aself * x4.y;
    acc.z = aself * x4.z; acc.w = aself * x4.w;
#pragma unroll 8
    for (int j = 0; j < DEG; ++j) {
      float a = al[j];
      float4 v = ((float4*)xl)[(int)sp[j] * 16 + c4];
      acc.x += a * v.x; acc.y += a * v.y;
      acc.z += a * v.z; acc.w += a * v.w;
    }
    acc.x += bgv.x; acc.y += bgv.y; acc.z += bgv.z; acc.w += bgv.w;
    ((float4*)out)[(size_t)(base + d) * 32 + h * 16 + c4] = acc;
  }
}

// ---- out-GEMM: h = lrelu(g@lW + lb); lW streamed (32 KB, ~L1-resident) ----
__global__ __launch_bounds__(256) void k_out_gemm(
    const float* __restrict__ gin, const float* __restrict__ lW,
    const float* __restrict__ lb, float* __restrict__ h,
    float* __restrict__ partial) {
  __shared__ __align__(16) float gl[64 * 132];           // 33.8 KB
  __shared__ float psum[2 * HID];
  int t = threadIdx.x;
  int n0 = blockIdx.x * 64;

  for (int u = t; u < 64 * 32; u += 256) {
    int r = u >> 5, q = u & 31;
    int n = n0 + r;
    float4 v = make_float4(0.f, 0.f, 0.f, 0.f);
    if (n < NN) v = ((const float4*)(gin + (size_t)n * HC))[q];
    ((float4*)(gl + r * 132))[q] = v;
  }
  if (t < 2 * HID) psum[t] = 0.f;
  __syncthreads();

  int ng = t >> 4, cg = t & 15;   // 16 node-groups x 16 col-groups(float4)
  int r0 = ng * 4;
  float4 acc[4];
#pragma unroll
  for (int i = 0; i < 4; ++i) acc[i] = make_float4(0.f, 0.f, 0.f, 0.f);

  const float4* lW4 = (const float4*)lW;
  float4 w4 = lW4[cg];
  for (int k = 0; k < HC; ++k) {
    float4 wc = w4;
    if (k + 1 < HC) w4 = lW4[(k + 1) * 16 + cg];
#pragma unroll
    for (int i = 0; i < 4; ++i) {
      float a = gl[(r0 + i) * 132 + k];
      acc[i].x += a * wc.x; acc[i].y += a * wc.y;
      acc[i].z += a * wc.z; acc[i].w += a * wc.w;
    }
  }
  float4 bias = ((const float4*)lb)[cg];
  float s0 = 0, s1 = 0, s2 = 0, s3 = 0, q0 = 0, q1 = 0, q2 = 0, q3 = 0;
#pragma unroll
  for (int i = 0; i < 4; ++i) {
    int n = n0 + r0 + i;
    if (n < NN) {
      float4 v;
      v.x = lrelu(acc[i].x + bias.x); v.y = lrelu(acc[i].y + bias.y);
      v.z = lrelu(acc[i].z + bias.z); v.w = lrelu(acc[i].w + bias.w);
      ((float4*)(h + (size_t)n * HID))[cg] = v;
      s0 += v.x; q0 += v.x * v.x; s1 += v.y; q1 += v.y * v.y;
      s2 += v.z; q2 += v.z * v.z; s3 += v.w; q3 += v.w * v.w;
    }
  }
  int c0 = cg * 4;
  atomicAdd(&psum[c0 + 0], s0); atomicAdd(&psum[c0 + 1], s1);
  atomicAdd(&psum[c0 + 2], s2); atomicAdd(&psum[c0 + 3], s3);
  atomicAdd(&psum[HID + c0 + 0], q0); atomicAdd(&psum[HID + c0 + 1], q1);
  atomicAdd(&psum[HID + c0 + 2], q2); atomicAdd(&psum[HID + c0 + 3], q3);
  __syncthreads();
  if (t < 2 * HID) partial[blockIdx.x * 128 + t] = psum[t];
}

// ---- stats: reduce partials -> BN fold coefficients A,B ----
__global__ __launch_bounds__(256) void k_stats(
    const float* __restrict__ partial, int nb, const float* __restrict__ gamma,
    const float* __restrict__ beta, float* __restrict__ AB) {
  __shared__ float red[2][256];
  int c = blockIdx.x, t = threadIdx.x;
  float s = 0.f, sq = 0.f;
  for (int i = t; i < nb; i += 256) {
    s += partial[i * 128 + c];
    sq += partial[i * 128 + 64 + c];
  }
  red[0][t] = s; red[1][t] = sq;
  __syncthreads();
  for (int o = 128; o > 0; o >>= 1) {
    if (t < o) { red[0][t] += red[0][t + o]; red[1][t] += red[1][t + o]; }
    __syncthreads();
  }
  if (t == 0) {
    float mean = red[0][0] / (float)NN;
    float var = red[1][0] / (float)NN - mean * mean;
    float A = gamma[c] * rsqrtf(var + 1e-5f);
    AB[c] = A;
    AB[64 + c] = beta[c] - mean * A;
  }
}

// ---- pool + MLP head: per-graph mean of BN(h2) -> 64 -> 32 -> 2 ----
__global__ __launch_bounds__(64) void k_pool_mlp(
    const float* __restrict__ h2, const float* __restrict__ AB,
    const float* __restrict__ f1W, const float* __restrict__ f1b,
    const float* __restrict__ f2W, const float* __restrict__ f2b,
    const float* __restrict__ f3W, const float* __restrict__ f3b,
    float* __restrict__ out) {
  __shared__ float pp[4 * 64];
  __shared__ float pooled[64];
  __shared__ float z1[64];
  __shared__ float z2[32];
  int g = blockIdx.x, t = threadIdx.x;
  const float4* hb4 = (const float4*)(h2 + (size_t)g * NPGc * HID);
  int rq = t >> 4, c4 = t & 15;
  float4 s4 = make_float4(0.f, 0.f, 0.f, 0.f);
  for (int r = rq; r < NPGc; r += 4) {
    float4 v = hb4[r * 16 + c4];
    s4.x += v.x; s4.y += v.y; s4.z += v.z; s4.w += v.w;
  }
  ((float4*)pp)[rq * 16 + c4] = s4;
  __syncthreads();
  pooled[t] = (pp[t] + pp[64 + t] + pp[128 + t] + pp[192 + t]) * (1.0f / NPGc) * AB[t] + AB[64 + t];
  __syncthreads();
  float a = f1b[t];
  for (int c = 0; c < 64; ++c) a += pooled[c] * f1W[c * 64 + t];
  z1[t] = lrelu(a);
  __syncthreads();
  if (t < 32) {
    float a2 = f2b[t];
    for (int c = 0; c < 64; ++c) a2 += z1[c] * f2W[c * 32 + t];
    z2[t] = lrelu(a2);
  }
  __syncthreads();
  if (t < 2) {
    float a3 = f3b[t];
    for (int c = 0; c < 32; ++c) a3 += z2[c] * f3W[c * 2 + t];
    out[g * 2 + t] = a3;
  }
}

extern "C" void kernel_launch(void* const* d_in, const int* in_sizes, int n_in,
                              void* d_out, int out_size, void* d_ws, size_t ws_size,
                              hipStream_t stream) {
  const float* x   = (const float*)d_in[0];
  const float* W1  = (const float*)d_in[2];
  const float* as1 = (const float*)d_in[3];
  const float* ad1 = (const float*)d_in[4];
  const float* bg1 = (const float*)d_in[5];
  const float* l1W = (const float*)d_in[6];
  const float* l1b = (const float*)d_in[7];
  const float* g1  = (const float*)d_in[8];
  const float* b1  = (const float*)d_in[9];
  const float* W2  = (const float*)d_in[10];
  const float* as2 = (const float*)d_in[11];
  const float* ad2 = (const float*)d_in[12];
  const float* bg2 = (const float*)d_in[13];
  const float* l2W = (const float*)d_in[14];
  const float* l2b = (const float*)d_in[15];
  const float* g2  = (const float*)d_in[16];
  const float* b2  = (const float*)d_in[17];
  const float* f1W = (const float*)d_in[18];
  const float* f1b = (const float*)d_in[19];
  const float* f2W = (const float*)d_in[20];
  const float* f2b = (const float*)d_in[21];
  const float* f3W = (const float*)d_in[22];
  const float* f3b = (const float*)d_in[23];
  const int* esrc  = (const int*)d_in[24];   // row 0 of edge_index
  float* out = (float*)d_out;

  float* ws = (float*)d_ws;
  size_t off = 0;
  auto alloc = [&](size_t nf) { float* p = ws + off; off += (nf + 63) & ~(size_t)63; return p; };
  float* Wa1     = alloc(100 * 4);
  float* Wa2     = alloc(64 * 4);
  float* xp      = alloc((size_t)NN * HC);
  float* ssrc    = alloc((size_t)NN * 2);
  float* sdst    = alloc((size_t)NN * 2);
  float* gout    = alloc((size_t)NN * HC);
  float* hbuf    = alloc((size_t)NN * HID);
  const int NB = (NN + 63) / 64;   // 782
  float* partial = alloc((size_t)NB * 128);
  float* AB1     = alloc(128);
  float* AB2     = alloc(128);
  (void)in_sizes; (void)n_in; (void)out_size; (void)ws_size;

  k_prep<<<2, 256, 0, stream>>>(W1, as1, ad1, Wa1, W2, as2, ad2, Wa2);
  k_in_gemm<100, false><<<NB * 2, 256, 0, stream>>>(x, W1, Wa1, nullptr, xp, ssrc, sdst);
  k_gat<<<NG * 2, 256, 0, stream>>>(xp, ssrc, sdst, esrc, bg1, gout);
  k_out_gemm<<<NB, 256, 0, stream>>>(gout, l1W, l1b, hbuf, partial);
  k_stats<<<64, 256, 0, stream>>>(partial, NB, g1, b1, AB1);
  k_in_gemm<64, true><<<NB * 2, 256, 0, stream>>>(hbuf, W2, Wa2, AB1, xp, ssrc, sdst);
  k_gat<<<NG * 2, 256, 0, stream>>>(xp, ssrc, sdst, esrc, bg2, gout);
  k_out_gemm<<<NB, 256, 0, stream>>>(gout, l2W, l2b, hbuf, partial);
  k_stats<<<64, 256, 0, stream>>>(partial, NB, g2, b2, AB2);
  k_pool_mlp<<<NG, 64, 0, stream>>>(hbuf, AB2, f1W, f1b, f2W, f2b, f3W, f3b, out);
}

// Round 13
// 320.390 us; speedup vs baseline: 1.4574x; 1.0199x over previous
//
#include <hip/hip_runtime.h>

#define NN 50000
#define NPGc 100
#define NG 500
#define DEG 32
#define HC 128
#define HID 64

__device__ __forceinline__ float lrelu(float x) { return x > 0.0f ? x : 0.2f * x; }

// ---- prep: Wa[K][4] = [ W@as_h0 | W@as_h1 | W@ad_h0 | W@ad_h1 ] for both layers ----
__global__ void k_prep(const float* __restrict__ W1, const float* __restrict__ as1,
                       const float* __restrict__ ad1, float* __restrict__ Wa1,
                       const float* __restrict__ W2, const float* __restrict__ as2,
                       const float* __restrict__ ad2, float* __restrict__ Wa2) {
  const float* W  = blockIdx.x ? W2 : W1;
  const float* as_ = blockIdx.x ? as2 : as1;
  const float* ad_ = blockIdx.x ? ad2 : ad1;
  float* Wa = blockIdx.x ? Wa2 : Wa1;
  int K = blockIdx.x ? 64 : 100;
  int t = threadIdx.x;
  for (int u = t; u < K * 4; u += blockDim.x) {
    int k = u >> 2, s = u & 3;
    const float* a = (s < 2) ? as_ : ad_;
    int h = s & 1;
    float acc = 0.f;
    for (int c = 0; c < 64; ++c) acc += W[k * 128 + h * 64 + c] * a[h * 64 + c];
    Wa[k * 4 + s] = acc;
  }
}

// ---- in-GEMM, per-(node-tile, head) block: 64 nodes x 64 cols.
//      W half staged in LDS (no global latency in inner loop). ----
template <int K, bool BN>
__global__ __launch_bounds__(256) void k_in_gemm(
    const float* __restrict__ in, const float* __restrict__ W,
    const float* __restrict__ Wa, const float* __restrict__ AB,
    float* __restrict__ xp, float* __restrict__ ssrc, float* __restrict__ sdst) {
  constexpr int KP = (K % 8 == 0) ? K + 4 : K;   // pad when K%8==0 (bank spread)
  __shared__ __align__(16) float xs[64 * KP];    // 25.6 KB (K=100) / 17.4 KB (K=64)
  __shared__ __align__(16) float wl[K * 64];     // 25.6 KB (K=100) / 16.0 KB (K=64)
  int t = threadIdx.x;
  int b = blockIdx.x >> 1, h = blockIdx.x & 1;
  int n0 = b * 64;

  // stage this head's W columns: wl[k][0..63] = W[k][h*64 .. h*64+63]
  const float4* W4 = (const float4*)W;
  for (int u = t; u < K * 16; u += 256)
    ((float4*)wl)[u] = W4[(u >> 4) * 32 + h * 16 + (u & 15)];

  constexpr int RQ = K / 4;
  for (int u = t; u < 64 * RQ; u += 256) {
    int r = u / RQ, q = u % RQ;
    int n = n0 + r;
    float4 v = make_float4(0.f, 0.f, 0.f, 0.f);
    if (n < NN) v = ((const float4*)(in + (size_t)n * K))[q];
    if (BN) {
      float4 a4 = ((const float4*)AB)[q];
      float4 b4 = ((const float4*)(AB + 64))[q];
      v.x = v.x * a4.x + b4.x; v.y = v.y * a4.y + b4.y;
      v.z = v.z * a4.z + b4.z; v.w = v.w * a4.w + b4.w;
    }
    ((float4*)(xs + r * KP))[q] = v;
  }
  __syncthreads();

  int ng = t >> 4, cg = t & 15;   // 16 node-groups x 16 col-f4 (of this head)
  int r0 = ng * 4;
  float4 acc[4];
#pragma unroll
  for (int i = 0; i < 4; ++i) acc[i] = make_float4(0.f, 0.f, 0.f, 0.f);

  for (int k = 0; k < K; ++k) {
    float4 wc = ((float4*)wl)[k * 16 + cg];
#pragma unroll
    for (int i = 0; i < 4; ++i) {
      float a = xs[(r0 + i) * KP + k];
      acc[i].x += a * wc.x; acc[i].y += a * wc.y;
      acc[i].z += a * wc.z; acc[i].w += a * wc.w;
    }
  }
#pragma unroll
  for (int i = 0; i < 4; ++i) {
    int n = n0 + r0 + i;
    if (n < NN) ((float4*)(xp + (size_t)n * HC))[h * 16 + cg] = acc[i];
  }
  // score columns for this head: 64 nodes x {src,dst}
  if (t < 128) {
    int r = t >> 1, s = t & 1;
    float sc = 0.f;
    for (int k = 0; k < K; ++k) sc += xs[r * KP + k] * Wa[k * 4 + s * 2 + h];
    int n = n0 + r;
    if (n < NN) {
      if (s == 0) ssrc[n * 2 + h] = sc;
      else        sdst[n * 2 + h] = sc;
    }
  }
}

// ---- GAT: per-(graph,head) block; edge softmax + aggregation from LDS ----
__global__ __launch_bounds__(256) void k_gat(
    const float* __restrict__ xp, const float* __restrict__ ssrc,
    const float* __restrict__ sdst, const int* __restrict__ esrc,
    const float* __restrict__ bg, float* __restrict__ out) {
  __shared__ __align__(16) float xl[NPGc * 64];          // 25.6 KB (this head's cols)
  __shared__ float sh[NPGc];
  __shared__ float sdh[NPGc];
  __shared__ unsigned short srcl[NPGc * DEG];            // 6.4 KB
  __shared__ float alpha[NPGc * (DEG + 2)];              // 13.6 KB
  int t = threadIdx.x;
  int g = blockIdx.x >> 1, h = blockIdx.x & 1;
  int base = g * NPGc;

  const float4* xp4 = (const float4*)(xp + (size_t)base * HC);
  for (int u = t; u < NPGc * 16; u += 256)
    ((float4*)xl)[u] = xp4[(u >> 4) * 32 + h * 16 + (u & 15)];
  if (t < NPGc) {
    sh[t] = ssrc[(base + t) * 2 + h];
    sdh[t] = sdst[(base + t) * 2 + h];
  }
  for (int u = t; u < NPGc * DEG; u += 256)
    srcl[u] = (unsigned short)(esrc[base * DEG + u] - base);
  __syncthreads();

  if (t < NPGc) {
    float sd = sdh[t];
    float es = lrelu(sh[t] + sd);   // self-loop score
    float m = es;
    float e[DEG];
#pragma unroll
    for (int j = 0; j < DEG; ++j) {
      e[j] = lrelu(sh[srcl[t * DEG + j]] + sd);
      m = fmaxf(m, e[j]);
    }
    float exs = __expf(es - m);
    float den = exs;
#pragma unroll
    for (int j = 0; j < DEG; ++j) { e[j] = __expf(e[j] - m); den += e[j]; }
    float inv = 1.0f / den;
    float* al = alpha + t * (DEG + 2);
#pragma unroll
    for (int j = 0; j < DEG; ++j) al[j] = e[j] * inv;
    al[DEG] = exs * inv;
  }
  __syncthreads();

  int c4 = t & 15;                         // loop-invariant (256 % 16 == 0)
  float4 bgv = ((const float4*)bg)[h * 16 + c4];
  for (int d = t >> 4; d < NPGc; d += 16) {
    const float* al = alpha + d * (DEG + 2);
    const unsigned short* sp = srcl + d * DEG;
    float aself = al[DEG];
    float4 x4 = ((float4*)xl)[d * 16 + c4];
    float4 acc;
    acc.x = aself * x4.x; acc.y = aself * x4.y;
    acc.z = aself * x4.z; acc.w = aself * x4.w;
#pragma unroll 8
    for (int j = 0; j < DEG; ++j) {
      float a = al[j];
      float4 v = ((float4*)xl)[(int)sp[j] * 16 + c4];
      acc.x += a * v.x; acc.y += a * v.y;
      acc.z += a * v.z; acc.w += a * v.w;
    }
    acc.x += bgv.x; acc.y += bgv.y; acc.z += bgv.z; acc.w += bgv.w;
    ((float4*)out)[(size_t)(base + d) * 32 + h * 16 + c4] = acc;
  }
}

// ---- out-GEMM: h = lrelu(g@lW + lb); lW streamed (32 KB, ~L1-resident) ----
__global__ __launch_bounds__(256) void k_out_gemm(
    const float* __restrict__ gin, const float* __restrict__ lW,
    const float* __restrict__ lb, float* __restrict__ h,
    float* __restrict__ partial) {
  __shared__ __align__(16) float gl[64 * 132];           // 33.8 KB
  __shared__ float psum[2 * HID];
  int t = threadIdx.x;
  int n0 = blockIdx.x * 64;

  for (int u = t; u < 64 * 32; u += 256) {
    int r = u >> 5, q = u & 31;
    int n = n0 + r;
    float4 v = make_float4(0.f, 0.f, 0.f, 0.f);
    if (n < NN) v = ((const float4*)(gin + (size_t)n * HC))[q];
    ((float4*)(gl + r * 132))[q] = v;
  }
  if (t < 2 * HID) psum[t] = 0.f;
  __syncthreads();

  int ng = t >> 4, cg = t & 15;   // 16 node-groups x 16 col-groups(float4)
  int r0 = ng * 4;
  float4 acc[4];
#pragma unroll
  for (int i = 0; i < 4; ++i) acc[i] = make_float4(0.f, 0.f, 0.f, 0.f);

  const float4* lW4 = (const float4*)lW;
  float4 w4 = lW4[cg];
  for (int k = 0; k < HC; ++k) {
    float4 wc = w4;
    if (k + 1 < HC) w4 = lW4[(k + 1) * 16 + cg];
#pragma unroll
    for (int i = 0; i < 4; ++i) {
      float a = gl[(r0 + i) * 132 + k];
      acc[i].x += a * wc.x; acc[i].y += a * wc.y;
      acc[i].z += a * wc.z; acc[i].w += a * wc.w;
    }
  }
  float4 bias = ((const float4*)lb)[cg];
  float s0 = 0, s1 = 0, s2 = 0, s3 = 0, q0 = 0, q1 = 0, q2 = 0, q3 = 0;
#pragma unroll
  for (int i = 0; i < 4; ++i) {
    int n = n0 + r0 + i;
    if (n < NN) {
      float4 v;
      v.x = lrelu(acc[i].x + bias.x); v.y = lrelu(acc[i].y + bias.y);
      v.z = lrelu(acc[i].z + bias.z); v.w = lrelu(acc[i].w + bias.w);
      ((float4*)(h + (size_t)n * HID))[cg] = v;
      s0 += v.x; q0 += v.x * v.x; s1 += v.y; q1 += v.y * v.y;
      s2 += v.z; q2 += v.z * v.z; s3 += v.w; q3 += v.w * v.w;
    }
  }
  int c0 = cg * 4;
  atomicAdd(&psum[c0 + 0], s0); atomicAdd(&psum[c0 + 1], s1);
  atomicAdd(&psum[c0 + 2], s2); atomicAdd(&psum[c0 + 3], s3);
  atomicAdd(&psum[HID + c0 + 0], q0); atomicAdd(&psum[HID + c0 + 1], q1);
  atomicAdd(&psum[HID + c0 + 2], q2); atomicAdd(&psum[HID + c0 + 3], q3);
  __syncthreads();
  if (t < 2 * HID) partial[blockIdx.x * 128 + t] = psum[t];
}

// ---- stats: reduce partials -> BN fold coefficients A,B ----
__global__ __launch_bounds__(256) void k_stats(
    const float* __restrict__ partial, int nb, const float* __restrict__ gamma,
    const float* __restrict__ beta, float* __restrict__ AB) {
  __shared__ float red[2][256];
  int c = blockIdx.x, t = threadIdx.x;
  float s = 0.f, sq = 0.f;
  for (int i = t; i < nb; i += 256) {
    s += partial[i * 128 + c];
    sq += partial[i * 128 + 64 + c];
  }
  red[0][t] = s; red[1][t] = sq;
  __syncthreads();
  for (int o = 128; o > 0; o >>= 1) {
    if (t < o) { red[0][t] += red[0][t + o]; red[1][t] += red[1][t + o]; }
    __syncthreads();
  }
  if (t == 0) {
    float mean = red[0][0] / (float)NN;
    float var = red[1][0] / (float)NN - mean * mean;
    float A = gamma[c] * rsqrtf(var + 1e-5f);
    AB[c] = A;
    AB[64 + c] = beta[c] - mean * A;
  }
}

// ---- pool + MLP head: per-graph mean of BN(h2) -> 64 -> 32 -> 2 ----
__global__ __launch_bounds__(64) void k_pool_mlp(
    const float* __restrict__ h2, const float* __restrict__ AB,
    const float* __restrict__ f1W, const float* __restrict__ f1b,
    const float* __restrict__ f2W, const float* __restrict__ f2b,
    const float* __restrict__ f3W, const float* __restrict__ f3b,
    float* __restrict__ out) {
  __shared__ float pp[4 * 64];
  __shared__ float pooled[64];
  __shared__ float z1[64];
  __shared__ float z2[32];
  int g = blockIdx.x, t = threadIdx.x;
  const float4* hb4 = (const float4*)(h2 + (size_t)g * NPGc * HID);
  int rq = t >> 4, c4 = t & 15;
  float4 s4 = make_float4(0.f, 0.f, 0.f, 0.f);
  for (int r = rq; r < NPGc; r += 4) {
    float4 v = hb4[r * 16 + c4];
    s4.x += v.x; s4.y += v.y; s4.z += v.z; s4.w += v.w;
  }
  ((float4*)pp)[rq * 16 + c4] = s4;
  __syncthreads();
  pooled[t] = (pp[t] + pp[64 + t] + pp[128 + t] + pp[192 + t]) * (1.0f / NPGc) * AB[t] + AB[64 + t];
  __syncthreads();
  float a = f1b[t];
  for (int c = 0; c < 64; ++c) a += pooled[c] * f1W[c * 64 + t];
  z1[t] = lrelu(a);
  __syncthreads();
  if (t < 32) {
    float a2 = f2b[t];
    for (int c = 0; c < 64; ++c) a2 += z1[c] * f2W[c * 32 + t];
    z2[t] = lrelu(a2);
  }
  __syncthreads();
  if (t < 2) {
    float a3 = f3b[t];
    for (int c = 0; c < 32; ++c) a3 += z2[c] * f3W[c * 2 + t];
    out[g * 2 + t] = a3;
  }
}

extern "C" void kernel_launch(void* const* d_in, const int* in_sizes, int n_in,
                              void* d_out, int out_size, void* d_ws, size_t ws_size,
                              hipStream_t stream) {
  const float* x   = (const float*)d_in[0];
  const float* W1  = (const float*)d_in[2];
  const float* as1 = (const float*)d_in[3];
  const float* ad1 = (const float*)d_in[4];
  const float* bg1 = (const float*)d_in[5];
  const float* l1W = (const float*)d_in[6];
  const float* l1b = (const float*)d_in[7];
  const float* g1  = (const float*)d_in[8];
  const float* b1  = (const float*)d_in[9];
  const float* W2  = (const float*)d_in[10];
  const float* as2 = (const float*)d_in[11];
  const float* ad2 = (const float*)d_in[12];
  const float* bg2 = (const float*)d_in[13];
  const float* l2W = (const float*)d_in[14];
  const float* l2b = (const float*)d_in[15];
  const float* g2  = (const float*)d_in[16];
  const float* b2  = (const float*)d_in[17];
  const float* f1W = (const float*)d_in[18];
  const float* f1b = (const float*)d_in[19];
  const float* f2W = (const float*)d_in[20];
  const float* f2b = (const float*)d_in[21];
  const float* f3W = (const float*)d_in[22];
  const float* f3b = (const float*)d_in[23];
  const int* esrc  = (const int*)d_in[24];   // row 0 of edge_index
  float* out = (float*)d_out;

  float* ws = (float*)d_ws;
  size_t off = 0;
  auto alloc = [&](size_t nf) { float* p = ws + off; off += (nf + 63) & ~(size_t)63; return p; };
  float* Wa1     = alloc(100 * 4);
  float* Wa2     = alloc(64 * 4);
  float* xp      = alloc((size_t)NN * HC);
  float* ssrc    = alloc((size_t)NN * 2);
  float* sdst    = alloc((size_t)NN * 2);
  float* gout    = alloc((size_t)NN * HC);
  float* hbuf    = alloc((size_t)NN * HID);
  const int NB = (NN + 63) / 64;   // 782
  float* partial = alloc((size_t)NB * 128);
  float* AB1     = alloc(128);
  float* AB2     = alloc(128);
  (void)in_sizes; (void)n_in; (void)out_size; (void)ws_size;

  k_prep<<<2, 256, 0, stream>>>(W1, as1, ad1, Wa1, W2, as2, ad2, Wa2);
  k_in_gemm<100, false><<<NB * 2, 256, 0, stream>>>(x, W1, Wa1, nullptr, xp, ssrc, sdst);
  k_gat<<<NG * 2, 256, 0, stream>>>(xp, ssrc, sdst, esrc, bg1, gout);
  k_out_gemm<<<NB, 256, 0, stream>>>(gout, l1W, l1b, hbuf, partial);
  k_stats<<<64, 256, 0, stream>>>(partial, NB, g1, b1, AB1);
  k_in_gemm<64, true><<<NB * 2, 256, 0, stream>>>(hbuf, W2, Wa2, AB1, xp, ssrc, sdst);
  k_gat<<<NG * 2, 256, 0, stream>>>(xp, ssrc, sdst, esrc, bg2, gout);
  k_out_gemm<<<NB, 256, 0, stream>>>(gout, l2W, l2b, hbuf, partial);
  k_stats<<<64, 256, 0, stream>>>(partial, NB, g2, b2, AB2);
  k_pool_mlp<<<NG, 64, 0, stream>>>(hbuf, AB2, f1W, f1b, f2W, f2b, f3W, f3b, out);
}